// Round 5
// baseline (268.278 us; speedup 1.0000x reference)
//
#include <hip/hip_runtime.h>

#define NB 8
#define NA 32
#define NS 16
#define KE 18750        // floats per emotion row
#define K3 43500        // floats per 3dmm row
#define KH_E 9375       // float2 per emotion row
#define KH_3 21750      // float2 per 3dmm row
#define ND3 58
#define NKL 262144      // 4*8*16*512

#define SE_SLABS 5
#define SD_SLABS 11
#define SLABS 16        // 5 E + 11 D
#define TRIPS 8
#define CH2 2048        // float2 per slab = TRIPS*256
#define COST_BLOCKS (NB * 8 * SLABS)   // 1024
#define KL_BLOCKS 64
#define KL_PER_THR (NKL / (KL_BLOCKS * 256))   // 16

// sqrt of per-term weights (folded into both operands at load)
#define SW_E  0.0073029674f   // sqrt(1/18750)
#define SW_1  0.0050637127f   // sqrt(1/39000)
#define SW_2  0.0471404521f   // sqrt(10/4500)

// ---------------------------------------------------------------------------
// blocks [0, COST_BLOCKS): decomposed pairwise cost
//   cross[b,s,a] += sum_k w_k p_k g_k       (8x8 register tile, butterfly)
//   normP[b,s]   += sum_k w_k p_k^2 / 4     (every block; x4 multiplicity)
//   normG[b,a]   += sum_k w_k g_k^2 / 2     (every block; x2 multiplicity)
// blocks [COST_BLOCKS, +KL_BLOCKS): KL partial sums -> atomic klsum
// ---------------------------------------------------------------------------
__global__ __launch_bounds__(256, 3) void fused_kernel(
    const float* __restrict__ ge, const float* __restrict__ g3,
    const float* __restrict__ pe, const float* __restrict__ p3,
    const float* __restrict__ mu, const float* __restrict__ sc,
    float* __restrict__ cross, float* __restrict__ normP,
    float* __restrict__ normG, float* __restrict__ klsum)
{
    const int blk = blockIdx.x;
    const int tid = threadIdx.x;
    __shared__ float red[4][64];

    if (blk >= COST_BLOCKS) {
        // ---------------- KL part ----------------
        const int kb = blk - COST_BLOCKS;
        float ks = 0.f;
        #pragma unroll
        for (int it = 0; it < KL_PER_THR; ++it) {
            const int i = kb * (256 * KL_PER_THR) + it * 256 + tid;
            const float m = mu[i], sg = sc[i];
            ks += 0.5f * (sg * sg + m * m - 1.0f) - logf(sg);
        }
        #pragma unroll
        for (int o = 32; o > 0; o >>= 1) ks += __shfl_xor(ks, o);
        const int lane = tid & 63, w = tid >> 6;
        if (lane == 0) red[0][w] = ks;
        __syncthreads();
        if (tid == 0)
            atomicAdd(klsum, red[0][0] + red[0][1] + red[0][2] + red[0][3]);
        return;
    }

    // ---------------- pairwise cost part ----------------
    const int b     = blk >> 7;          // 128 blocks per b
    const int rem   = blk & 127;
    const int pos   = rem >> 4;
    const int slab  = rem & 15;
    const int stile = pos >> 2;          // 0..1
    const int atile = pos & 3;           // 0..3
    const int s0    = stile * 8;
    const int a0    = atile * 8;

    const bool isE  = slab < SE_SLABS;
    const int  KH   = isE ? KH_E : KH_3;
    const int  base = (isE ? slab : slab - SE_SLABS) * CH2;

    const float2* __restrict__ P = (const float2*)(isE ? pe + (size_t)(b * NS + s0) * KE
                                                       : p3 + (size_t)(b * NS + s0) * K3);
    const float2* __restrict__ G = (const float2*)(isE ? ge + (size_t)(b * NA + a0) * KE
                                                       : g3 + (size_t)(b * NA + a0) * K3);

    float acc[64];
    #pragma unroll
    for (int i = 0; i < 64; ++i) acc[i] = 0.f;
    float np[8], ng[8];
    #pragma unroll
    for (int i = 0; i < 8; ++i) { np[i] = 0.f; ng[i] = 0.f; }

    int col = (2 * (base + tid)) % ND3;   // only used in the D branch

    #pragma unroll
    for (int it = 0; it < TRIPS; ++it) {
        const int  kk    = base + it * 256 + tid;
        const bool valid = kk < KH;
        const int  kc    = valid ? kk : (KH - 1);
        float sw;
        if (isE) {
            sw = valid ? SW_E : 0.f;
        } else {
            sw = valid ? ((col < 52) ? SW_1 : SW_2) : 0.f;
            col += 48; if (col >= ND3) col -= ND3;     // advance by 512 % 58
        }

        float2 p[8], g[8];
        #pragma unroll
        for (int i = 0; i < 8; ++i) p[i] = P[i * KH + kc];
        #pragma unroll
        for (int j = 0; j < 8; ++j) g[j] = G[j * KH + kc];
        #pragma unroll
        for (int i = 0; i < 8; ++i) { p[i].x *= sw; p[i].y *= sw; }
        #pragma unroll
        for (int j = 0; j < 8; ++j) { g[j].x *= sw; g[j].y *= sw; }

        #pragma unroll
        for (int i = 0; i < 8; ++i)
            np[i] = fmaf(p[i].y, p[i].y, fmaf(p[i].x, p[i].x, np[i]));
        #pragma unroll
        for (int j = 0; j < 8; ++j)
            ng[j] = fmaf(g[j].y, g[j].y, fmaf(g[j].x, g[j].x, ng[j]));

        #pragma unroll
        for (int i = 0; i < 8; ++i)
            #pragma unroll
            for (int j = 0; j < 8; ++j) {
                float t = fmaf(p[i].x, g[j].x, acc[i * 8 + j]);
                acc[i * 8 + j] = fmaf(p[i].y, g[j].y, t);
            }
    }

    const int lane = tid & 63;
    const int w    = tid >> 6;

    // ---- norm reduction: full-wave sum of np[8], ng[8] ----
    #pragma unroll
    for (int i = 0; i < 8; ++i) {
        #pragma unroll
        for (int o = 32; o > 0; o >>= 1) {
            np[i] += __shfl_xor(np[i], o);
            ng[i] += __shfl_xor(ng[i], o);
        }
    }
    if (lane == 0) {
        #pragma unroll
        for (int i = 0; i < 8; ++i) { red[w][i] = np[i]; red[w][8 + i] = ng[i]; }
    }
    __syncthreads();
    if (tid < 8) {
        const float v = red[0][tid] + red[1][tid] + red[2][tid] + red[3][tid];
        atomicAdd(&normP[b * NS + s0 + tid], v * 0.25f);
    } else if (tid < 16) {
        const int j = tid - 8;
        const float v = red[0][tid] + red[1][tid] + red[2][tid] + red[3][tid];
        atomicAdd(&normG[b * NA + a0 + j], v * 0.5f);
    }
    __syncthreads();

    // ---- cross reduction: value-splitting butterfly (63 shfl+add) ----
    int n = 64;
    #pragma unroll
    for (int step = 0; step < 6; ++step) {
        const int o = 1 << step;
        const bool hi = (lane & o) != 0;
        const int h = n >> 1;
        #pragma unroll
        for (int m = 0; m < h; ++m) {
            const float send = hi ? acc[m] : acc[m + h];
            const float recv = __shfl_xor(send, o);
            acc[m] = (hi ? acc[m + h] : acc[m]) + recv;
        }
        n = h;
    }
    red[w][__brev((unsigned)lane) >> 26] = acc[0];
    __syncthreads();
    if (tid < 64) {
        const float v = red[0][tid] + red[1][tid] + red[2][tid] + red[3][tid];
        const int i = tid >> 3, j = tid & 7;
        atomicAdd(&cross[(b * NS + s0 + i) * NA + (a0 + j)], v);
    }
}

// ---------------------------------------------------------------------------
// 1 block x 128 threads: t=(b,s); cost = normP + normG - 2*cross; min over a.
// ---------------------------------------------------------------------------
__global__ __launch_bounds__(128) void finalize_kernel(
    const float* __restrict__ cross, const float* __restrict__ normP,
    const float* __restrict__ normG, const float* __restrict__ klsum,
    float* __restrict__ out)
{
    const int t = threadIdx.x;
    const int b = t >> 4;
    const float npv = normP[t];
    const float* cr = cross + t * NA;
    const float* ngr = normG + b * NA;
    float mn = 1e30f;
    #pragma unroll
    for (int a = 0; a < NA; ++a)
        mn = fminf(mn, npv + ngr[a] - 2.0f * cr[a]);

    #pragma unroll
    for (int o = 32; o > 0; o >>= 1) mn += __shfl_xor(mn, o);
    __shared__ float r2[2];
    if ((t & 63) == 0) r2[t >> 6] = mn;
    __syncthreads();
    if (t == 0) {
        const float rec = (r2[0] + r2[1]) * (1.0f / (NB * NS));
        const float kld = klsum[0] * (1.0f / (float)NKL);
        out[0] = fmaf(0.0002f, kld, rec);
        out[1] = rec;
        out[2] = kld;
    }
}

extern "C" void kernel_launch(void* const* d_in, const int* in_sizes, int n_in,
                              void* d_out, int out_size, void* d_ws, size_t ws_size,
                              hipStream_t stream)
{
    const float* ge = (const float*)d_in[0];
    const float* g3 = (const float*)d_in[1];
    const float* pe = (const float*)d_in[2];
    const float* p3 = (const float*)d_in[3];
    const float* mu = (const float*)d_in[4];
    const float* sc = (const float*)d_in[5];

    float* cross = (float*)d_ws;                   // 4096
    float* normP = cross + NB * NS * NA;           // 128
    float* normG = normP + NB * NS;                // 256
    float* klsum = normG + NB * NA;                // 1

    hipMemsetAsync(d_ws, 0, (NB * NS * NA + NB * NS + NB * NA + 1) * sizeof(float), stream);

    fused_kernel<<<COST_BLOCKS + KL_BLOCKS, 256, 0, stream>>>(
        ge, g3, pe, p3, mu, sc, cross, normP, normG, klsum);
    finalize_kernel<<<1, 128, 0, stream>>>(cross, normP, normG, klsum, (float*)d_out);
}

// Round 6
// 188.040 us; speedup vs baseline: 1.4267x; 1.4267x over previous
//
#include <hip/hip_runtime.h>

#define NB 8
#define NA 32
#define NS 16
#define KE 18750        // floats per emotion row
#define K3 43500        // floats per 3dmm row
#define KH_E 9375       // float2 per emotion row
#define KQ_3 10875      // float4 per 3dmm row
#define ND3 58
#define NKL 262144      // 4*8*16*512

#define SE_SLABS 5
#define SD_SLABS 11
#define SLABS 16        // 5 E + 11 D
#define CHE 1875        // float2 per E slab (5*1875 = 9375 exact)
#define CHD 989         // float4 per D slab (11th slab gets 985)
#define COST_BLOCKS (NB * 8 * SLABS)   // 1024
#define KL_BLOCKS 64
#define KL_PER_THR (NKL / (KL_BLOCKS * 256))   // 16

#define SW_1 0.0050637127f    // sqrt(1/39000)
#define SW_2 0.0471404521f    // sqrt(10/4500)
#define W_E  (1.0f / 18750.0f)

// ---------------------------------------------------------------------------
// blocks [0, COST_BLOCKS): pairwise weighted-SSD slab partials -> atomic cost
//   E slabs: raw SSD (uniform weight applied once at the atomic)
//   D slabs: float4 loads, per-component sqrt-weights on both operands
// blocks [COST_BLOCKS, +KL_BLOCKS): KL partial sums -> atomic klsum
// ---------------------------------------------------------------------------
__global__ __launch_bounds__(256, 3) void fused_kernel(
    const float* __restrict__ ge, const float* __restrict__ g3,
    const float* __restrict__ pe, const float* __restrict__ p3,
    const float* __restrict__ mu, const float* __restrict__ sc,
    float* __restrict__ cost, float* __restrict__ klsum)
{
    const int blk = blockIdx.x;
    const int tid = threadIdx.x;
    __shared__ float red[4][64];

    if (blk >= COST_BLOCKS) {
        // ---------------- KL part ----------------
        const int kb = blk - COST_BLOCKS;
        float ks = 0.f;
        #pragma unroll
        for (int it = 0; it < KL_PER_THR; ++it) {
            const int i = kb * (256 * KL_PER_THR) + it * 256 + tid;
            const float m = mu[i], sg = sc[i];
            ks += 0.5f * (sg * sg + m * m - 1.0f) - logf(sg);
        }
        #pragma unroll
        for (int o = 32; o > 0; o >>= 1) ks += __shfl_xor(ks, o);
        const int lane = tid & 63, w = tid >> 6;
        if (lane == 0) red[0][w] = ks;
        __syncthreads();
        if (tid == 0)
            atomicAdd(klsum, red[0][0] + red[0][1] + red[0][2] + red[0][3]);
        return;
    }

    // ---------------- pairwise cost part ----------------
    const int b    = blk >> 7;           // 128 blocks per b
    const int rem  = blk & 127;
    const int pos  = rem >> 4;
    const int slab = rem & 15;
    const int s0   = (pos >> 2) * 8;
    const int a0   = (pos & 3) * 8;

    const bool isE = slab < SE_SLABS;

    float acc[64];
    #pragma unroll
    for (int i = 0; i < 64; ++i) acc[i] = 0.f;

    if (isE) {
        // ---- emotion: float2, unweighted SSD ----
        const int base = slab * CHE;
        const int kend = base + CHE;                 // 5*1875 = 9375 exact
        const float2* __restrict__ P = (const float2*)(pe + (size_t)(b * NS + s0) * KE);
        const float2* __restrict__ G = (const float2*)(ge + (size_t)(b * NA + a0) * KE);

        #pragma unroll 1
        for (int kk = base + tid; kk < kend; kk += 256) {
            float2 p[8], g[8];
            #pragma unroll
            for (int i = 0; i < 8; ++i) p[i] = P[i * KH_E + kk];
            #pragma unroll
            for (int j = 0; j < 8; ++j) g[j] = G[j * KH_E + kk];
            #pragma unroll
            for (int i = 0; i < 8; ++i)
                #pragma unroll
                for (int j = 0; j < 8; ++j) {
                    const float d0 = p[i].x - g[j].x;
                    const float d1 = p[i].y - g[j].y;
                    float t = fmaf(d0, d0, acc[i * 8 + j]);
                    acc[i * 8 + j] = fmaf(d1, d1, t);
                }
        }
    } else {
        // ---- 3dmm: float4, per-component sqrt-weights on both operands ----
        const int dslab = slab - SE_SLABS;
        const int base  = dslab * CHD;
        const int kend  = min(base + CHD, KQ_3);
        const float4* __restrict__ P = (const float4*)(p3 + (size_t)(b * NS + s0) * K3);
        const float4* __restrict__ G = (const float4*)(g3 + (size_t)(b * NA + a0) * K3);

        int c0 = (4 * (base + tid)) % ND3;   // col of component .x

        #pragma unroll 1
        for (int kk = base + tid; kk < kend; kk += 256) {
            // component cols c0..c0+3 (c0 <= 57); col>=58 wraps to 0..2 (<52)
            const float w0 = (c0 >= 52 && c0 < 58) ? SW_2 : SW_1;
            const float w1 = (c0 + 1 >= 52 && c0 + 1 < 58) ? SW_2 : SW_1;
            const float w2 = (c0 + 2 >= 52 && c0 + 2 < 58) ? SW_2 : SW_1;
            const float w3 = (c0 + 3 >= 52 && c0 + 3 < 58) ? SW_2 : SW_1;
            c0 += 38; if (c0 >= ND3) c0 -= ND3;      // advance by 1024 % 58

            float4 p[8], g[8];
            #pragma unroll
            for (int i = 0; i < 8; ++i) p[i] = P[i * KQ_3 + kk];
            #pragma unroll
            for (int j = 0; j < 8; ++j) g[j] = G[j * KQ_3 + kk];
            #pragma unroll
            for (int i = 0; i < 8; ++i) {
                p[i].x *= w0; p[i].y *= w1; p[i].z *= w2; p[i].w *= w3;
            }
            #pragma unroll
            for (int j = 0; j < 8; ++j) {
                g[j].x *= w0; g[j].y *= w1; g[j].z *= w2; g[j].w *= w3;
            }
            #pragma unroll
            for (int i = 0; i < 8; ++i)
                #pragma unroll
                for (int j = 0; j < 8; ++j) {
                    const float d0 = p[i].x - g[j].x;
                    const float d1 = p[i].y - g[j].y;
                    const float d2 = p[i].z - g[j].z;
                    const float d3 = p[i].w - g[j].w;
                    float t = fmaf(d0, d0, acc[i * 8 + j]);
                    t = fmaf(d1, d1, t);
                    t = fmaf(d2, d2, t);
                    acc[i * 8 + j] = fmaf(d3, d3, t);
                }
        }
    }

    // ---- cross reduction: value-splitting butterfly (63 shfl+add) ----
    const int lane = tid & 63;
    int n = 64;
    #pragma unroll
    for (int step = 0; step < 6; ++step) {
        const int o = 1 << step;
        const bool hi = (lane & o) != 0;
        const int h = n >> 1;
        #pragma unroll
        for (int m = 0; m < h; ++m) {
            const float send = hi ? acc[m] : acc[m + h];
            const float recv = __shfl_xor(send, o);
            acc[m] = (hi ? acc[m + h] : acc[m]) + recv;
        }
        n = h;
    }

    const int w = tid >> 6;
    red[w][__brev((unsigned)lane) >> 26] = acc[0];
    __syncthreads();
    if (tid < 64) {
        float v = red[0][tid] + red[1][tid] + red[2][tid] + red[3][tid];
        if (isE) v *= W_E;
        const int i = tid >> 3, j = tid & 7;
        atomicAdd(&cost[b * (NS * NA) + (s0 + i) * NA + (a0 + j)], v);
    }
}

// 1 block x 128 threads: thread t = (b,s); min over a, mean, add KL.
__global__ __launch_bounds__(128) void finalize_kernel(
    const float* __restrict__ cost, const float* __restrict__ klsum,
    float* __restrict__ out)
{
    const int t = threadIdx.x;
    const float4* row = (const float4*)(cost + t * NA);
    float mn = 1e30f;
    #pragma unroll
    for (int q = 0; q < 8; ++q) {
        const float4 v = row[q];
        mn = fminf(mn, fminf(fminf(v.x, v.y), fminf(v.z, v.w)));
    }
    #pragma unroll
    for (int o = 32; o > 0; o >>= 1) mn += __shfl_xor(mn, o);
    __shared__ float r2[2];
    if ((t & 63) == 0) r2[t >> 6] = mn;
    __syncthreads();
    if (t == 0) {
        const float rec = (r2[0] + r2[1]) * (1.0f / (NB * NS));
        const float kld = klsum[0] * (1.0f / (float)NKL);
        out[0] = fmaf(0.0002f, kld, rec);
        out[1] = rec;
        out[2] = kld;
    }
}

extern "C" void kernel_launch(void* const* d_in, const int* in_sizes, int n_in,
                              void* d_out, int out_size, void* d_ws, size_t ws_size,
                              hipStream_t stream)
{
    const float* ge = (const float*)d_in[0];
    const float* g3 = (const float*)d_in[1];
    const float* pe = (const float*)d_in[2];
    const float* p3 = (const float*)d_in[3];
    const float* mu = (const float*)d_in[4];
    const float* sc = (const float*)d_in[5];

    float* cost  = (float*)d_ws;            // 4096 floats
    float* klsum = cost + NB * NS * NA;     // 1 float

    hipMemsetAsync(d_ws, 0, (NB * NS * NA + 1) * sizeof(float), stream);

    fused_kernel<<<COST_BLOCKS + KL_BLOCKS, 256, 0, stream>>>(
        ge, g3, pe, p3, mu, sc, cost, klsum);
    finalize_kernel<<<1, 128, 0, stream>>>(cost, klsum, (float*)d_out);
}

// Round 7
// 145.902 us; speedup vs baseline: 1.8388x; 1.2888x over previous
//
#include <hip/hip_runtime.h>

#define NB 8
#define NA 32
#define NS 16
#define KE 18750        // floats per emotion row
#define K3 43500        // floats per 3dmm row
#define KH_E 9375       // float2 per emotion row
#define KH_3 21750      // float2 per 3dmm row
#define ND3 58
#define NKL 262144      // 4*8*16*512

#define SE_SLABS 5
#define SD_SLABS 11
#define SLABS 16        // 5 E + 11 D per (b,pos)
#define CHE 1875        // float2 per E slab (5*1875 = 9375 exact)
#define CHD 1978        // float2 per D slab (11*1978 = 21758 >= 21750)
#define COST_BLOCKS (NB * 8 * SLABS)   // 1024
#define KL_BLOCKS 64
#define KL_PER_THR (NKL / (KL_BLOCKS * 256))   // 16

#define SW_1 0.0050637127f    // sqrt(1/39000)
#define SW_2 0.0471404521f    // sqrt(10/4500)
#define W_E  (1.0f / 18750.0f)

// ---------------------------------------------------------------------------
// blocks [0, COST_BLOCKS): pairwise weighted-SSD slab partials -> atomic cost
//   float2 loads, register double-buffer (prefetch next iter's 16 loads
//   before the current FMA block). E: unweighted, scaled once at the atomic.
// blocks [COST_BLOCKS, +KL_BLOCKS): KL partial sums -> atomic klsum
// ---------------------------------------------------------------------------
__global__ __launch_bounds__(256, 3) void fused_kernel(
    const float* __restrict__ ge, const float* __restrict__ g3,
    const float* __restrict__ pe, const float* __restrict__ p3,
    const float* __restrict__ mu, const float* __restrict__ sc,
    float* __restrict__ cost, float* __restrict__ klsum)
{
    const int blk = blockIdx.x;
    const int tid = threadIdx.x;
    __shared__ float red[4][64];

    if (blk >= COST_BLOCKS) {
        // ---------------- KL part ----------------
        const int kb = blk - COST_BLOCKS;
        float ks = 0.f;
        #pragma unroll
        for (int it = 0; it < KL_PER_THR; ++it) {
            const int i = kb * (256 * KL_PER_THR) + it * 256 + tid;
            const float m = mu[i], sg = sc[i];
            ks += 0.5f * (sg * sg + m * m - 1.0f) - logf(sg);
        }
        #pragma unroll
        for (int o = 32; o > 0; o >>= 1) ks += __shfl_xor(ks, o);
        const int lane = tid & 63, w = tid >> 6;
        if (lane == 0) red[0][w] = ks;
        __syncthreads();
        if (tid == 0)
            atomicAdd(klsum, red[0][0] + red[0][1] + red[0][2] + red[0][3]);
        return;
    }

    // ---------------- pairwise cost part ----------------
    const int b    = blk >> 7;           // 128 blocks per b
    const int rem  = blk & 127;
    const int pos  = rem >> 4;
    const int slab = rem & 15;
    const int s0   = (pos >> 2) * 8;
    const int a0   = (pos & 3) * 8;

    const bool isE = slab < SE_SLABS;

    float acc[64];
    #pragma unroll
    for (int i = 0; i < 64; ++i) acc[i] = 0.f;

    if (isE) {
        // ---- emotion: float2, unweighted SSD, depth-1 prefetch ----
        const int base = slab * CHE;
        const int kend = base + CHE;
        const float2* __restrict__ P = (const float2*)(pe + (size_t)(b * NS + s0) * KE);
        const float2* __restrict__ G = (const float2*)(ge + (size_t)(b * NA + a0) * KE);

        int kk = base + tid;             // tid < 256 < CHE, so first iter valid
        float2 p[8], g[8];
        #pragma unroll
        for (int i = 0; i < 8; ++i) p[i] = P[i * KH_E + kk];
        #pragma unroll
        for (int j = 0; j < 8; ++j) g[j] = G[j * KH_E + kk];

        #pragma unroll 1
        while (kk < kend) {
            const int knext = kk + 256;
            const int kload = (knext < kend) ? knext : kk;   // tail: re-load cur
            float2 pn[8], gn[8];
            #pragma unroll
            for (int i = 0; i < 8; ++i) pn[i] = P[i * KH_E + kload];
            #pragma unroll
            for (int j = 0; j < 8; ++j) gn[j] = G[j * KH_E + kload];

            #pragma unroll
            for (int i = 0; i < 8; ++i)
                #pragma unroll
                for (int j = 0; j < 8; ++j) {
                    const float d0 = p[i].x - g[j].x;
                    const float d1 = p[i].y - g[j].y;
                    float t = fmaf(d0, d0, acc[i * 8 + j]);
                    acc[i * 8 + j] = fmaf(d1, d1, t);
                }

            #pragma unroll
            for (int i = 0; i < 8; ++i) { p[i] = pn[i]; g[i] = gn[i]; }
            kk = knext;
        }
    } else {
        // ---- 3dmm: float2, per-iter uniform weight (52 even), prefetch ----
        const int base = (slab - SE_SLABS) * CHD;
        const int kend = min(base + CHD, KH_3);
        const float2* __restrict__ P = (const float2*)(p3 + (size_t)(b * NS + s0) * K3);
        const float2* __restrict__ G = (const float2*)(g3 + (size_t)(b * NA + a0) * K3);

        int kk = base + tid;             // tid < 256 < CHD, first iter valid
        int col = (2 * kk) % ND3;        // even; both float2 comps same side
        float2 p[8], g[8];
        #pragma unroll
        for (int i = 0; i < 8; ++i) p[i] = P[i * KH_3 + kk];
        #pragma unroll
        for (int j = 0; j < 8; ++j) g[j] = G[j * KH_3 + kk];

        #pragma unroll 1
        while (kk < kend) {
            const int knext = kk + 256;
            const int kload = (knext < kend) ? knext : kk;
            float2 pn[8], gn[8];
            #pragma unroll
            for (int i = 0; i < 8; ++i) pn[i] = P[i * KH_3 + kload];
            #pragma unroll
            for (int j = 0; j < 8; ++j) gn[j] = G[j * KH_3 + kload];

            const float sw = (col < 52) ? SW_1 : SW_2;
            col += 48; if (col >= ND3) col -= ND3;    // advance by 512 % 58

            float2 ps[8], gs[8];
            #pragma unroll
            for (int i = 0; i < 8; ++i) { ps[i].x = p[i].x * sw; ps[i].y = p[i].y * sw; }
            #pragma unroll
            for (int j = 0; j < 8; ++j) { gs[j].x = g[j].x * sw; gs[j].y = g[j].y * sw; }

            #pragma unroll
            for (int i = 0; i < 8; ++i)
                #pragma unroll
                for (int j = 0; j < 8; ++j) {
                    const float d0 = ps[i].x - gs[j].x;
                    const float d1 = ps[i].y - gs[j].y;
                    float t = fmaf(d0, d0, acc[i * 8 + j]);
                    acc[i * 8 + j] = fmaf(d1, d1, t);
                }

            #pragma unroll
            for (int i = 0; i < 8; ++i) { p[i] = pn[i]; g[i] = gn[i]; }
            kk = knext;
        }
    }

    // ---- cross reduction: value-splitting butterfly (63 shfl+add) ----
    const int lane = tid & 63;
    int n = 64;
    #pragma unroll
    for (int step = 0; step < 6; ++step) {
        const int o = 1 << step;
        const bool hi = (lane & o) != 0;
        const int h = n >> 1;
        #pragma unroll
        for (int m = 0; m < h; ++m) {
            const float send = hi ? acc[m] : acc[m + h];
            const float recv = __shfl_xor(send, o);
            acc[m] = (hi ? acc[m + h] : acc[m]) + recv;
        }
        n = h;
    }

    const int w = tid >> 6;
    red[w][__brev((unsigned)lane) >> 26] = acc[0];
    __syncthreads();
    if (tid < 64) {
        float v = red[0][tid] + red[1][tid] + red[2][tid] + red[3][tid];
        if (isE) v *= W_E;
        const int i = tid >> 3, j = tid & 7;
        atomicAdd(&cost[b * (NS * NA) + (s0 + i) * NA + (a0 + j)], v);
    }
}

// 1 block x 128 threads: thread t = (b,s); min over a, mean, add KL.
__global__ __launch_bounds__(128) void finalize_kernel(
    const float* __restrict__ cost, const float* __restrict__ klsum,
    float* __restrict__ out)
{
    const int t = threadIdx.x;
    const float4* row = (const float4*)(cost + t * NA);
    float mn = 1e30f;
    #pragma unroll
    for (int q = 0; q < 8; ++q) {
        const float4 v = row[q];
        mn = fminf(mn, fminf(fminf(v.x, v.y), fminf(v.z, v.w)));
    }
    #pragma unroll
    for (int o = 32; o > 0; o >>= 1) mn += __shfl_xor(mn, o);
    __shared__ float r2[2];
    if ((t & 63) == 0) r2[t >> 6] = mn;
    __syncthreads();
    if (t == 0) {
        const float rec = (r2[0] + r2[1]) * (1.0f / (NB * NS));
        const float kld = klsum[0] * (1.0f / (float)NKL);
        out[0] = fmaf(0.0002f, kld, rec);
        out[1] = rec;
        out[2] = kld;
    }
}

extern "C" void kernel_launch(void* const* d_in, const int* in_sizes, int n_in,
                              void* d_out, int out_size, void* d_ws, size_t ws_size,
                              hipStream_t stream)
{
    const float* ge = (const float*)d_in[0];
    const float* g3 = (const float*)d_in[1];
    const float* pe = (const float*)d_in[2];
    const float* p3 = (const float*)d_in[3];
    const float* mu = (const float*)d_in[4];
    const float* sc = (const float*)d_in[5];

    float* cost  = (float*)d_ws;            // 4096 floats
    float* klsum = cost + NB * NS * NA;     // 1 float

    hipMemsetAsync(d_ws, 0, (NB * NS * NA + 1) * sizeof(float), stream);

    fused_kernel<<<COST_BLOCKS + KL_BLOCKS, 256, 0, stream>>>(
        ge, g3, pe, p3, mu, sc, cost, klsum);
    finalize_kernel<<<1, 128, 0, stream>>>(cost, klsum, (float*)d_out);
}